// Round 1
// baseline (971.889 us; speedup 1.0000x reference)
//
#include <hip/hip_runtime.h>
#include <cstdint>

#define HDIM 64

// ---------------- edge dtype detection (int64 vs int32) ----------------
// If edge_index is int64 (values < 2^31, >=0), every odd uint32 word is 0.
// For int32 random indices in [0,1e5), 128 consecutive zeros is impossible.
__global__ void k_detect(const unsigned* ei, int* flag) {
    if (threadIdx.x == 0) {
        int all0 = 1;
        for (int i = 1; i < 256; i += 2)
            if (ei[i] != 0u) { all0 = 0; break; }
        *flag = all0;  // 1 => int64
    }
}

__device__ __forceinline__ int edge_val(const void* ei, int is64, long long idx) {
    if (is64) return (int)((const long long*)ei)[idx];
    return ((const int*)ei)[idx];
}

// ---------------- CSR build ----------------
__global__ void k_zero2(int* a, int* b, int n) {
    int i = blockIdx.x * blockDim.x + threadIdx.x;
    if (i < n) { a[i] = 0; b[i] = 0; }
}

__global__ void k_count(const void* ei, const int* flag, int* cnt, int E) {
    int e = blockIdx.x * blockDim.x + threadIdx.x;
    if (e < E) {
        int d = edge_val(ei, *flag, (long long)E + e);  // dst row
        atomicAdd(&cnt[d], 1);
    }
}

// exclusive scan over n+1 entries (a[i] = i<n ? cnt[i] : 0) -> rowptr[0..n]
__global__ __launch_bounds__(1024) void k_scan1(const int* cnt, int* rowptr, int* bsum, int n) {
    __shared__ int sm[1024];
    int tid = threadIdx.x;
    int i = blockIdx.x * 1024 + tid;
    int v = (i < n) ? cnt[i] : 0;
    sm[tid] = v;
    __syncthreads();
    for (int off = 1; off < 1024; off <<= 1) {
        int t = (tid >= off) ? sm[tid - off] : 0;
        __syncthreads();
        sm[tid] += t;
        __syncthreads();
    }
    if (i <= n) rowptr[i] = sm[tid] - v;   // exclusive
    if (tid == 1023) bsum[blockIdx.x] = sm[1023];
}

__global__ void k_scan2(int* bsum, int nb) {
    if (threadIdx.x == 0) {
        int acc = 0;
        for (int i = 0; i < nb; i++) { int v = bsum[i]; bsum[i] = acc; acc += v; }
    }
}

__global__ __launch_bounds__(1024) void k_scan3(int* rowptr, const int* bsum, const int* cnt,
                                                float* dis, int n) {
    int i = blockIdx.x * 1024 + threadIdx.x;
    if (i <= n) rowptr[i] += bsum[blockIdx.x];
    if (i < n) dis[i] = rsqrtf((float)(cnt[i] + 1));   // deg = edge-count + self-loop
}

__global__ void k_fill(const void* ei, const int* flag, const int* rowptr, int* fill,
                       int* col, int E) {
    int e = blockIdx.x * blockDim.x + threadIdx.x;
    if (e < E) {
        int is64 = *flag;
        int d = edge_val(ei, is64, (long long)E + e);
        int s = edge_val(ei, is64, (long long)e);
        int pos = rowptr[d] + atomicAdd(&fill[d], 1);
        col[pos] = s;
    }
}

// ---------------- g = dis[i] * (in @ W)   [N,K]@[K,64] ----------------
template <int K>
__global__ __launch_bounds__(256) void k_gemm_scale(const float* __restrict__ in,
                                                    const float* __restrict__ W,
                                                    const float* __restrict__ dis,
                                                    float* __restrict__ g, int n) {
    __shared__ float wlds[K * HDIM];
    for (int i = threadIdx.x; i < K * HDIM; i += blockDim.x) wlds[i] = W[i];
    __syncthreads();
    int lane = threadIdx.x & 63;
    int wid = threadIdx.x >> 6;
    int nw = blockDim.x >> 6;
    for (int r = blockIdx.x * nw + wid; r < n; r += gridDim.x * nw) {
        const float4* xr = (const float4*)(in + (size_t)r * K);
        float acc = 0.f;
#pragma unroll
        for (int k4 = 0; k4 < K / 4; k4++) {
            float4 xv = xr[k4];
            acc = fmaf(xv.x, wlds[(k4 * 4 + 0) * HDIM + lane], acc);
            acc = fmaf(xv.y, wlds[(k4 * 4 + 1) * HDIM + lane], acc);
            acc = fmaf(xv.z, wlds[(k4 * 4 + 2) * HDIM + lane], acc);
            acc = fmaf(xv.w, wlds[(k4 * 4 + 3) * HDIM + lane], acc);
        }
        g[(size_t)r * HDIM + lane] = acc * dis[r];
    }
}

// ---------------- out[d] = [relu]( dis[d]*(g[d] + sum_e g[col[e]]) + b ) ----------------
template <bool RELU>
__global__ __launch_bounds__(256) void k_aggregate(const float* __restrict__ g,
                                                   const int* __restrict__ rowptr,
                                                   const int* __restrict__ col,
                                                   const float* __restrict__ dis,
                                                   const float* __restrict__ bias,
                                                   float* __restrict__ out, int n) {
    int lane = threadIdx.x & 63;
    int wid = threadIdx.x >> 6;
    int node = blockIdx.x * (blockDim.x >> 6) + wid;
    if (node >= n) return;
    float s = g[(size_t)node * HDIM + lane];
    int e = rowptr[node], end = rowptr[node + 1];
    for (; e + 3 < end; e += 4) {
        int c0 = col[e], c1 = col[e + 1], c2 = col[e + 2], c3 = col[e + 3];
        float v0 = g[(size_t)c0 * HDIM + lane];
        float v1 = g[(size_t)c1 * HDIM + lane];
        float v2 = g[(size_t)c2 * HDIM + lane];
        float v3 = g[(size_t)c3 * HDIM + lane];
        s += (v0 + v1) + (v2 + v3);
    }
    for (; e < end; e++) s += g[(size_t)col[e] * HDIM + lane];
    float o = fmaf(dis[node], s, bias[lane]);
    if (RELU) o = fmaxf(o, 0.f);
    out[(size_t)node * HDIM + lane] = o;
}

extern "C" void kernel_launch(void* const* d_in, const int* in_sizes, int n_in,
                              void* d_out, int out_size, void* d_ws, size_t ws_size,
                              hipStream_t stream) {
    const float* x  = (const float*)d_in[0];
    const void*  ei = d_in[1];
    const float* W1 = (const float*)d_in[2];
    const float* b1 = (const float*)d_in[3];
    const float* W2 = (const float*)d_in[4];
    const float* b2 = (const float*)d_in[5];
    const float* W3 = (const float*)d_in[6];
    const float* b3 = (const float*)d_in[7];
    float* out = (float*)d_out;

    const int N = in_sizes[0] / 128;   // 100000
    const int E = in_sizes[1] / 2;     // 3200000

    // workspace carve-up (256B aligned)
    char* ws = (char*)d_ws;
    auto alloc = [&](size_t bytes) {
        char* p = ws;
        ws += ((bytes + 255) / 256) * 256;
        return p;
    };
    int*   flag   = (int*)alloc(4);
    int*   cnt    = (int*)alloc((size_t)N * 4);
    int*   fill   = (int*)alloc((size_t)N * 4);
    int*   rowptr = (int*)alloc((size_t)(N + 1) * 4);
    int*   bsum   = (int*)alloc(1024 * 4);
    float* dis    = (float*)alloc((size_t)N * 4);
    int*   col    = (int*)alloc((size_t)E * 4);
    float* bufA   = (float*)alloc((size_t)N * HDIM * 4);
    float* bufB   = (float*)alloc((size_t)N * HDIM * 4);

    const int NB = (N + 1 + 1023) / 1024;   // scan blocks over N+1 entries

    k_detect<<<1, 64, 0, stream>>>((const unsigned*)ei, flag);
    k_zero2<<<(N + 255) / 256, 256, 0, stream>>>(cnt, fill, N);
    k_count<<<(E + 255) / 256, 256, 0, stream>>>(ei, flag, cnt, E);
    k_scan1<<<NB, 1024, 0, stream>>>(cnt, rowptr, bsum, N);
    k_scan2<<<1, 64, 0, stream>>>(bsum, NB);
    k_scan3<<<NB, 1024, 0, stream>>>(rowptr, bsum, cnt, dis, N);
    k_fill<<<(E + 255) / 256, 256, 0, stream>>>(ei, flag, rowptr, fill, col, E);

    const int gemmGrid = 4096;
    const int aggGrid = (N + 3) / 4;

    // layer 1: g = dis*(x@W1); out1 = relu(dis*agg + b1)
    k_gemm_scale<128><<<gemmGrid, 256, 0, stream>>>(x, W1, dis, bufA, N);
    k_aggregate<true><<<aggGrid, 256, 0, stream>>>(bufA, rowptr, col, dis, b1, bufB, N);
    // layer 2
    k_gemm_scale<64><<<gemmGrid, 256, 0, stream>>>(bufB, W2, dis, bufA, N);
    k_aggregate<true><<<aggGrid, 256, 0, stream>>>(bufA, rowptr, col, dis, b2, bufB, N);
    // layer 3 (no relu) -> d_out
    k_gemm_scale<64><<<gemmGrid, 256, 0, stream>>>(bufB, W3, dis, bufA, N);
    k_aggregate<false><<<aggGrid, 256, 0, stream>>>(bufA, rowptr, col, dis, b3, out, N);
}